// Round 11
// baseline (84.889 us; speedup 1.0000x reference)
//
#include <hip/hip_runtime.h>
#include <hip/hip_fp16.h>
#include <math.h>

// GSchNet continuous-filter convolution edge embedding.
// out[e,:] = f(dist(e)) where f: R -> R^128 (RBF+MLP) is a smooth function of
// ONE scalar. Tabulate f on [0,16], lerp per edge.
//
// Ledger: R2/R5 baseline 114.1. R3/R4 multi-row A BANNED (real regression,
// mechanism unknown). R6 NT stores PERMANENT (+6 for plain, old structure).
// R7 TABK=1024 -> 105.9 (A-model verified, A~4us). R8 SW-pipeline: NEUTRAL
// (latency TLP-hidden). R9 f16 table: -3 (not read-BW-bound). R10 fuse B
// into C: -19.4 (83.6us) -> gather work hides inside C; spare issue capacity.
// R11 = ONE structural change to C's front-end: lane-parallel t-compute.
// Wave owns 64 edges; each LANE computes one edge's dist->t (coalesced idx,
// per-lane gathers, sqrt 1x instead of 32x); 16 sub-iters fetch t via __shfl
// (LDS pipe) and run the identical lerp+NT-store core. VMEM instrs per
// 64 edges: 352 -> 104. Tests the VMEM-issue-bound hypothesis.

#define N_NODES_C   50000
#define N_EDGES_C   800000
#define LATENT_C    128
#define N_CENTERS_C 100
#define TABK        1024
#define DMAX        16.0f
#define LN2F        0.69314718056f

typedef float  v4f __attribute__((ext_vector_type(4)));
typedef _Float16 h4 __attribute__((ext_vector_type(4)));

__device__ __forceinline__ float shifted_softplus(float x) {
    return fmaxf(x, 0.0f) + log1pf(expf(-fabsf(x))) - LN2F;
}

// -------- Phase A: one block (128 threads) per table row k, d = k*(DMAX/TABK)
// Stores f16 rows (256 B/row). [identical to R9/R10]
__global__ void build_table_kernel(const float* __restrict__ W1, const float* __restrict__ b1,
                                   const float* __restrict__ W2, const float* __restrict__ b2,
                                   _Float16* __restrict__ table) {
    __shared__ float rbf[N_CENTERS_C];
    __shared__ float hbuf[LATENT_C];
    const int j = threadIdx.x;
    const float d = (float)blockIdx.x * (DMAX / (float)TABK);

    if (j < N_CENTERS_C) {
        const float c = (float)j * (10.0f / 99.0f);   // linspace(0,10,100)
        const float x = d - c;
        rbf[j] = expf(-x * x);
    }
    __syncthreads();

    float a = b1[j];
    #pragma unroll 4
    for (int c = 0; c < N_CENTERS_C; ++c)
        a = fmaf(rbf[c], W1[c * LATENT_C + j], a);
    hbuf[j] = shifted_softplus(a);
    __syncthreads();

    float o = b2[j];
    #pragma unroll 4
    for (int i = 0; i < LATENT_C; ++i)
        o = fmaf(hbuf[i], W2[i * LATENT_C + j], o);

    table[(size_t)blockIdx.x * LATENT_C + j] = (_Float16)o;
}

// -------- Phase C: wave owns 64 edges. Scalar phase: lane l computes edge
// (base+l)'s dist -> t (coalesced senders/receivers loads, per-lane node
// gathers, ONE sqrt per edge). Write phase: 16 sub-iters x 4 edges; t via
// __shfl; f16-row lerp in f32; NT float4 stores (identical core to R10).
// Grid: 3125 blocks x 256 thr = 12500 waves x 64 edges = 800000 exactly.
__global__ void edge_write_kernel(const float* __restrict__ nodes,
                                  const int* __restrict__ senders,
                                  const int* __restrict__ receivers,
                                  const _Float16* __restrict__ table,
                                  float* __restrict__ out) {
    const int lane = threadIdx.x & 63;
    const int half = lane >> 5;          // edge within a store slot
    const int li   = lane & 31;          // half4 index within the 128-h row
    const int wid  = (blockIdx.x * blockDim.x + threadIdx.x) >> 6;
    const int base = wid * 64;

    // ---- scalar phase: one edge per lane
    const int e = base + lane;
    const int s = senders[e];
    const int r = receivers[e];
    const float dx = nodes[3 * s + 0] - nodes[3 * r + 0];
    const float dy = nodes[3 * s + 1] - nodes[3 * r + 1];
    const float dz = nodes[3 * s + 2] - nodes[3 * r + 2];
    const float dist = sqrtf(fmaf(dx, dx, fmaf(dy, dy, dz * dz)));
    // clamp so k+1 <= TABK stays in table
    const float t = fminf(dist * ((float)TABK / DMAX), (float)TABK - 0.5f);

    // ---- write phase: 4 edges per sub-iter (slot0: eb,eb+1; slot1: eb+2,eb+3)
    #pragma unroll 4
    for (int i = 0; i < 16; ++i) {
        const int eb = base + 4 * i;
        const float t0 = __shfl(t, 4 * i + half, 64);
        const float t1 = __shfl(t, 4 * i + 2 + half, 64);
        const int   k0 = (int)t0;  const float f0 = t0 - (float)k0;
        const int   k1 = (int)t1;  const float f1 = t1 - (float)k1;

        const h4* p0 = (const h4*)(table + (size_t)k0 * LATENT_C);
        const h4* p1 = (const h4*)(table + (size_t)k1 * LATENT_C);
        const h4 a0 = p0[li], b0 = p0[li + 32];   // +32 h4 = next row (k0+1)
        const h4 a1 = p1[li], b1 = p1[li + 32];

        v4f o0, o1;
        #pragma unroll
        for (int c = 0; c < 4; ++c) {
            const float A0 = (float)a0[c], B0 = (float)b0[c];
            const float A1 = (float)a1[c], B1 = (float)b1[c];
            o0[c] = fmaf(f0, B0 - A0, A0);
            o1[c] = fmaf(f1, B1 - A1, A1);
        }

        v4f* po0 = (v4f*)(out + (size_t)eb * LATENT_C);        // edges eb,eb+1
        v4f* po1 = (v4f*)(out + (size_t)(eb + 2) * LATENT_C);  // edges eb+2,eb+3
        __builtin_nontemporal_store(o0, &po0[lane]);
        __builtin_nontemporal_store(o1, &po1[lane]);
    }
}

// -------- Fallback (ws too small): direct per-edge MLP
__global__ void edge_direct_kernel(const float* __restrict__ nodes,
                                   const int* __restrict__ senders,
                                   const int* __restrict__ receivers,
                                   const float* __restrict__ W1, const float* __restrict__ b1,
                                   const float* __restrict__ W2, const float* __restrict__ b2,
                                   float* __restrict__ out) {
    __shared__ float rbf[N_CENTERS_C];
    __shared__ float hbuf[LATENT_C];
    const int j = threadIdx.x;

    for (int e = blockIdx.x; e < N_EDGES_C; e += gridDim.x) {
        const int s = senders[e];
        const int r = receivers[e];
        const float dx = nodes[3 * s + 0] - nodes[3 * r + 0];
        const float dy = nodes[3 * s + 1] - nodes[3 * r + 1];
        const float dz = nodes[3 * s + 2] - nodes[3 * r + 2];
        const float dist = sqrtf(fmaf(dx, dx, fmaf(dy, dy, dz * dz)));

        if (j < N_CENTERS_C) {
            const float c = (float)j * (10.0f / 99.0f);
            const float x = dist - c;
            rbf[j] = expf(-x * x);
        }
        __syncthreads();

        float a = b1[j];
        #pragma unroll 4
        for (int c = 0; c < N_CENTERS_C; ++c)
            a = fmaf(rbf[c], W1[c * LATENT_C + j], a);
        hbuf[j] = shifted_softplus(a);
        __syncthreads();

        float o = b2[j];
        #pragma unroll 4
        for (int i = 0; i < LATENT_C; ++i)
            o = fmaf(hbuf[i], W2[i * LATENT_C + j], o);
        out[(size_t)e * LATENT_C + j] = o;

        __syncthreads();
    }
}

extern "C" void kernel_launch(void* const* d_in, const int* in_sizes, int n_in,
                              void* d_out, int out_size, void* d_ws, size_t ws_size,
                              hipStream_t stream) {
    const float* nodes     = (const float*)d_in[0];
    const int*   senders   = (const int*)  d_in[1];
    const int*   receivers = (const int*)  d_in[2];
    const float* W1        = (const float*)d_in[3];
    const float* b1        = (const float*)d_in[4];
    const float* W2        = (const float*)d_in[5];
    const float* b2        = (const float*)d_in[6];
    float*       out       = (float*)d_out;

    const size_t table_bytes = (size_t)(TABK + 1) * LATENT_C * sizeof(_Float16); // 262,400

    if (ws_size >= table_bytes) {
        _Float16* table = (_Float16*)d_ws;

        build_table_kernel<<<TABK + 1, LATENT_C, 0, stream>>>(W1, b1, W2, b2, table);
        // 3125 blocks x 4 waves = 12500 waves x 64 edges = 800000 exactly.
        edge_write_kernel<<<3125, 256, 0, stream>>>(nodes, senders, receivers, table, out);
    } else {
        edge_direct_kernel<<<16384, LATENT_C, 0, stream>>>(nodes, senders, receivers,
                                                           W1, b1, W2, b2, out);
    }
}